// Round 2
// baseline (366.777 us; speedup 1.0000x reference)
//
#include <hip/hip_runtime.h>
#include <stdint.h>

#define NEGF   (-1.0e30f)
#define LOG2E  1.4426950408889634f
#define LN2    0.6931471805599453f
#define CH     32   // timesteps per register chunk in the recurrence

// lane i <- lane i-1 (whole wave), lane 0 <- NEG.  DPP wave_shr:1 = 0x138.
__device__ __forceinline__ float dpp_shr1(float x) {
  int r = __builtin_amdgcn_update_dpp(__float_as_int(NEGF), __float_as_int(x),
                                      0x138, 0xf, 0xf, false);
  return __int_as_float(r);
}

__device__ __forceinline__ float ladd2(float a, float b) {
  float m = fmaxf(a, b);
  float n = fminf(a, b);
  return m + log2f(1.0f + exp2f(n - m));
}

// ============================================================================
// Kernel 1: per (t,b) row: logsumexp over V, then emit compacted log2-softmax
// in TRANSPOSED layout lp[b][c][t], c=0 blank, c=1..L labels, stride Tp.
// blockIdx r -> b = r / T, t = r % T  (consecutive blocks share b, adjacent t
// -> transposed 4B writes from adjacent blocks coalesce in L2 lines).
// ============================================================================
__global__ __launch_bounds__(64) void k_lse_gather(
    const float* __restrict__ acts, const int* __restrict__ labels,
    float* __restrict__ lp, int T, int Tp, int B, int V, int L) {
  const uint32_t r = blockIdx.x;
  const uint32_t b = r / (uint32_t)T;
  const uint32_t t = r % (uint32_t)T;
  const int lane = threadIdx.x;
  const float* __restrict__ row = acts + ((size_t)t * (size_t)B + b) * (size_t)V;

  float mx, l2s;
  if (V == 2048) {
    const float4* row4 = (const float4*)row;
    float vals[32];
    mx = -3.0e38f;
#pragma unroll
    for (int q = 0; q < 8; ++q) {
      float4 v = row4[lane + (q << 6)];
      vals[q*4+0] = v.x; vals[q*4+1] = v.y; vals[q*4+2] = v.z; vals[q*4+3] = v.w;
      mx = fmaxf(mx, fmaxf(fmaxf(v.x, v.y), fmaxf(v.z, v.w)));
    }
#pragma unroll
    for (int off = 32; off >= 1; off >>= 1) mx = fmaxf(mx, __shfl_xor(mx, off, 64));
    float s = 0.0f;
#pragma unroll
    for (int k = 0; k < 32; ++k) s += exp2f((vals[k] - mx) * LOG2E);
#pragma unroll
    for (int off = 32; off >= 1; off >>= 1) s += __shfl_xor(s, off, 64);
    l2s = log2f(s);
  } else {
    float m = -3.0e38f, s = 0.0f;
    for (int i = lane; i < V; i += 64) {
      float x = row[i];
      float m2 = fmaxf(m, x);
      s = s * exp2f((m - m2) * LOG2E) + exp2f((x - m2) * LOG2E);
      m = m2;
    }
#pragma unroll
    for (int off = 32; off >= 1; off >>= 1) {
      float mo = __shfl_xor(m, off, 64), so = __shfl_xor(s, off, 64);
      float m2 = fmaxf(m, mo);
      s = s * exp2f((m - m2) * LOG2E) + so * exp2f((mo - m2) * LOG2E);
      m = m2;
    }
    mx = m;
    l2s = log2f(s);
  }

  float* __restrict__ out = lp + (size_t)b * (size_t)(L + 1) * (size_t)Tp;
  if (lane < L) {
    int lab = labels[b * (uint32_t)L + lane];
    out[(size_t)(1 + lane) * Tp + t] = (row[lab] - mx) * LOG2E - l2s;
  }
  if (lane == 0) out[t] = (row[0] - mx) * LOG2E - l2s;
}

// ============================================================================
// Kernel 2: CTC forward recurrence, one wave per batch element.
// Lane i owns states s0=2i (blank), s1=2i+1 (label i); lane 63 also s2=2L.
// lp consumed from transposed layout: per-lane contiguous-in-t channel,
// CH-step register double-buffer (float4 loads, 8+8 per chunk).
// ============================================================================
__global__ __launch_bounds__(64) void k_ctc_fwd(
    const float* __restrict__ lp, const int* __restrict__ labels,
    const int* __restrict__ act_lens, const int* __restrict__ label_lens,
    float* __restrict__ loss, int T, int Tp, int B, int L) {
  const int b = blockIdx.x;
  const int lane = threadIdx.x;
  const int Tact = __builtin_amdgcn_readfirstlane(min(act_lens[b], T));
  const int ll   = __builtin_amdgcn_readfirstlane(min(label_lens[b], L));

  const float* __restrict__ chb = lp + (size_t)b * (size_t)(L + 1) * (size_t)Tp;
  const float* __restrict__ chl = chb + (size_t)(1 + lane) * (size_t)Tp;

  int lab_i = (lane < L) ? labels[(size_t)b * L + lane] : 0;
  int lab_p = (lane >= 1 && lane - 1 < L) ? labels[(size_t)b * L + lane - 1] : -1;
  const bool allow2 = (lane >= 1) && (lab_i != 0) && (lab_i != lab_p);

  // t = 0 init
  float s0 = (lane == 0) ? chb[0] : NEGF;
  float s1 = (lane == 0) ? chl[0] : NEGF;
  float s2 = NEGF;

  float Ab[CH], Al[CH], Bb[CH], Bl[CH];

#define LOADC(BUF, t0) {                                                     \
    _Pragma("unroll")                                                        \
    for (int q = 0; q < CH / 4; ++q) {                                       \
      float4 v = *(const float4*)(chl + (t0) + 4 * q);                       \
      BUF##l[4*q+0] = v.x; BUF##l[4*q+1] = v.y;                              \
      BUF##l[4*q+2] = v.z; BUF##l[4*q+3] = v.w;                              \
      float4 w = *(const float4*)(chb + (t0) + 4 * q);                       \
      BUF##b[4*q+0] = w.x; BUF##b[4*q+1] = w.y;                              \
      BUF##b[4*q+2] = w.z; BUF##b[4*q+3] = w.w;                              \
    } }

#define STEP(LPB, LPL) {                                                     \
    float pa  = dpp_shr1(s1);                                                \
    float pb_ = dpp_shr1(s0);                                                \
    float c2  = allow2 ? pb_ : NEGF;                                         \
    float m0 = fmaxf(s0, pa), n0 = fminf(s0, pa);                            \
    float ns0 = (m0 + (LPB)) + log2f(1.0f + exp2f(n0 - m0));                 \
    float m1 = fmaxf(fmaxf(s1, s0), c2);                                     \
    float sS = exp2f(s1 - m1) + exp2f(s0 - m1) + exp2f(c2 - m1);             \
    float ns1 = (m1 + (LPL)) + log2f(sS);                                    \
    float m2 = fmaxf(s2, s1), n2 = fminf(s2, s1);                            \
    float ns2 = (m2 + (LPB)) + log2f(1.0f + exp2f(n2 - m2));                 \
    s0 = ns0; s1 = ns1; s2 = ns2; }

  // guarded step k of chunk starting at t0
#define SG(BUF, t0, k) { int t_ = (t0) + (k);                                \
    if (t_ >= 1 && t_ < Tact) STEP(BUF##b[k], BUF##l[k]) }

#define C8(BUF, t0, k0)                                                      \
    SG(BUF, t0, (k0)+0) SG(BUF, t0, (k0)+1) SG(BUF, t0, (k0)+2)              \
    SG(BUF, t0, (k0)+3) SG(BUF, t0, (k0)+4) SG(BUF, t0, (k0)+5)              \
    SG(BUF, t0, (k0)+6) SG(BUF, t0, (k0)+7)

#define CONSUME(BUF, t0) { C8(BUF, t0, 0) C8(BUF, t0, 8)                     \
                           C8(BUF, t0, 16) C8(BUF, t0, 24) }

  LOADC(A, 0);
  int t0 = 0;
  bool inA = true;
  for (;;) {
    bool haveNext = (t0 + CH < Tact);
    if (haveNext) {
      if (inA) LOADC(B, t0 + CH) else LOADC(A, t0 + CH)
    }
    if (inA) CONSUME(A, t0) else CONSUME(B, t0)
    if (!haveNext) break;
    t0 += CH;
    inA = !inA;
  }

#undef LOADC
#undef STEP
#undef SG
#undef C8
#undef CONSUME

  __shared__ float A_[132];
  A_[2 * lane] = s0;
  A_[2 * lane + 1] = s1;
  if (lane == 63) A_[128] = s2;
  __syncthreads();
  if (lane == 0) {
    int sl = 2 * ll;
    float a1 = A_[sl];
    float a2 = (sl >= 1) ? A_[sl - 1] : NEGF;
    loss[b] = -ladd2(a1, a2) * LN2;
  }
}

// ============================================================================
// Kernel 3: sum per-batch losses -> d_out[0]
// ============================================================================
__global__ __launch_bounds__(64) void k_sum(const float* __restrict__ loss,
                                            float* __restrict__ out, int B) {
  int lane = threadIdx.x;
  float s = 0.0f;
  for (int i = lane; i < B; i += 64) s += loss[i];
#pragma unroll
  for (int off = 32; off >= 1; off >>= 1) s += __shfl_xor(s, off, 64);
  if (lane == 0) out[0] = s;
}

extern "C" void kernel_launch(void* const* d_in, const int* in_sizes, int n_in,
                              void* d_out, int out_size, void* d_ws, size_t ws_size,
                              hipStream_t stream) {
  const float* acts       = (const float*)d_in[0];
  const int*   labels     = (const int*)d_in[1];
  const int*   act_lens   = (const int*)d_in[2];
  const int*   label_lens = (const int*)d_in[3];

  const int B = in_sizes[2];
  const int L = in_sizes[1] / B;
  const int T = 1000;   // per reference setup_inputs
  const int V = (int)((long long)in_sizes[0] / ((long long)T * (long long)B));
  const int Tp = (T + CH - 1) & ~(CH - 1);   // padded channel stride (1024)

  float* lp    = (float*)d_ws;                              // B*(L+1)*Tp floats
  float* lossb = lp + (size_t)B * (size_t)(L + 1) * (size_t)Tp;

  k_lse_gather<<<dim3(T * B), dim3(64), 0, stream>>>(acts, labels, lp, T, Tp, B, V, L);
  k_ctc_fwd<<<dim3(B), dim3(64), 0, stream>>>(lp, labels, act_lens, label_lens,
                                              lossb, T, Tp, B, L);
  k_sum<<<dim3(1), dim3(64), 0, stream>>>(lossb, (float*)d_out, B);
}

// Round 4
// 250.521 us; speedup vs baseline: 1.4641x; 1.4641x over previous
//
#include <hip/hip_runtime.h>
#include <stdint.h>

#define NEGF   (-1.0e30f)
#define LOG2E  1.4426950408889634f
#define LN2    0.6931471805599453f

// lane i <- lane i-1 (wave_shr:1 = 0x138), lane 0 <- NEGF (bound_ctrl=false, old)
__device__ __forceinline__ float dpp_shr1(float x) {
  int r = __builtin_amdgcn_update_dpp(__float_as_int(NEGF), __float_as_int(x),
                                      0x138, 0xf, 0xf, false);
  return __int_as_float(r);
}

__device__ __forceinline__ float ladd2(float a, float b) {
  float m = fmaxf(a, b);
  float n = fminf(a, b);
  return m + log2f(1.0f + exp2f(n - m));
}

// ============================================================================
// Kernel 1: per (t,b) row: logsumexp over V, emit LOG2-softmax probs,
// transposed layout lp[b][c][t], c=0 blank, c=1..L labels, stride Tp floats.
// 4 rows per 256-thread block (one wave each).
// ============================================================================
__global__ __launch_bounds__(256) void k_prob_gather(
    const float* __restrict__ acts, const int* __restrict__ labels,
    float* __restrict__ lp, int T, int Tp, int B, int V, int L) {
  const int lane = threadIdx.x & 63;
  const uint32_t r = blockIdx.x * 4u + (threadIdx.x >> 6);
  if (r >= (uint32_t)(T * B)) return;
  const uint32_t b = r / (uint32_t)T;
  const uint32_t t = r % (uint32_t)T;
  const float* __restrict__ row = acts + ((size_t)t * (size_t)B + b) * (size_t)V;

  float mx, l2s;
  if (V == 2048) {
    const float4* row4 = (const float4*)row;
    float vals[32];
    mx = -3.0e38f;
#pragma unroll
    for (int q = 0; q < 8; ++q) {
      float4 v = row4[lane + (q << 6)];
      vals[q*4+0] = v.x; vals[q*4+1] = v.y; vals[q*4+2] = v.z; vals[q*4+3] = v.w;
      mx = fmaxf(mx, fmaxf(fmaxf(v.x, v.y), fmaxf(v.z, v.w)));
    }
#pragma unroll
    for (int off = 32; off >= 1; off >>= 1) mx = fmaxf(mx, __shfl_xor(mx, off, 64));
    float s = 0.0f;
#pragma unroll
    for (int k = 0; k < 32; ++k) s += exp2f((vals[k] - mx) * LOG2E);
#pragma unroll
    for (int off = 32; off >= 1; off >>= 1) s += __shfl_xor(s, off, 64);
    l2s = log2f(s);
  } else {
    float m = -3.0e38f, s = 0.0f;
    for (int i = lane; i < V; i += 64) {
      float x = row[i];
      float m2 = fmaxf(m, x);
      s = s * exp2f((m - m2) * LOG2E) + exp2f((x - m2) * LOG2E);
      m = m2;
    }
#pragma unroll
    for (int off = 32; off >= 1; off >>= 1) {
      float mo = __shfl_xor(m, off, 64), so = __shfl_xor(s, off, 64);
      float m2 = fmaxf(m, mo);
      s = s * exp2f((m - m2) * LOG2E) + so * exp2f((mo - m2) * LOG2E);
      m = m2;
    }
    mx = m;
    l2s = log2f(s);
  }

  float* __restrict__ out = lp + (size_t)b * (size_t)(L + 1) * (size_t)Tp;
  if (lane < L) {
    int lab = labels[b * (uint32_t)L + lane];
    out[(size_t)(1 + lane) * Tp + t] = (row[lab] - mx) * LOG2E - l2s;
  }
  if (lane == 0) out[t] = (row[0] - mx) * LOG2E - l2s;
}

// ============================================================================
// Kernel 2: CTC forward recurrence, LOG2 domain (proven numerics), one wave
// per batch element. Lane i owns states s0=2i (blank), s1=2i+1 (label i);
// s2 duplicates state 2i+2 (lane 63's s2 = terminal blank 2L).
// Correct single-DPP step: skip source for label state 2i+1 is alpha[2i-1]
// = dpp(s1), the SAME value the blank update needs.
// Transposed lp: per-lane contiguous-in-t channel; 4 named-float4 windows
// (8 steps each) double-buffered 32 steps ahead — no spillable arrays.
// ============================================================================
__global__ __launch_bounds__(64) void k_ctc_fwd(
    const float* __restrict__ lp, const int* __restrict__ labels,
    const int* __restrict__ act_lens, const int* __restrict__ label_lens,
    float* __restrict__ loss, int T, int Tp, int B, int L) {
  const int b = blockIdx.x;
  const int lane = threadIdx.x;
  const int Tact = __builtin_amdgcn_readfirstlane(min(act_lens[b], T));
  const int ll   = __builtin_amdgcn_readfirstlane(min(label_lens[b], L));

  const float* __restrict__ chb = lp + (size_t)b * (size_t)(L + 1) * (size_t)Tp;
  const float* __restrict__ chl = chb + (size_t)(1 + lane) * (size_t)Tp;

  int lab_i = (lane < L) ? labels[(size_t)b * L + lane] : 0;
  int lab_p = (lane >= 1 && lane - 1 < L) ? labels[(size_t)b * L + lane - 1] : -1;
  const bool allow2 = (lane >= 1) && (lab_i != 0) && (lab_i != lab_p);

  float4 L0a,L0b,B0a,B0b, L1a,L1b,B1a,B1b, L2a,L2b,B2a,B2b, L3a,L3b,B3a,B3b;

#define LOADW(s, tt) { int tc = (tt); if (tc > Tp - 8) tc = Tp - 8;              \
    L##s##a = *(const float4*)(chl + tc); L##s##b = *(const float4*)(chl + tc + 4); \
    B##s##a = *(const float4*)(chb + tc); B##s##b = *(const float4*)(chb + tc + 4); }

  // log2-domain step; PB = log2 p_blank(t), PL = log2 p_label(t)
#define ST(PB, PL) { float pa = dpp_shr1(s1);                                    \
    float c2 = allow2 ? pa : NEGF;                                               \
    float m0 = fmaxf(s0, pa), n0 = fminf(s0, pa);                                \
    float ns0 = (m0 + (PB)) + log2f(1.0f + exp2f(n0 - m0));                      \
    float m1 = fmaxf(fmaxf(s1, s0), c2);                                         \
    float sS = exp2f(s1 - m1) + exp2f(s0 - m1) + exp2f(c2 - m1);                 \
    float ns1 = (m1 + (PL)) + log2f(sS);                                         \
    float m2 = fmaxf(s2, s1), n2 = fminf(s2, s1);                                \
    float ns2 = (m2 + (PB)) + log2f(1.0f + exp2f(n2 - m2));                      \
    s0 = ns0; s1 = ns1; s2 = ns2; }

#define PROCF(s) { ST(B##s##a.x, L##s##a.x) ST(B##s##a.y, L##s##a.y)             \
                   ST(B##s##a.z, L##s##a.z) ST(B##s##a.w, L##s##a.w)             \
                   ST(B##s##b.x, L##s##b.x) ST(B##s##b.y, L##s##b.y)             \
                   ST(B##s##b.z, L##s##b.z) ST(B##s##b.w, L##s##b.w) }

#define STG(PB, PL, tt) { if ((tt) >= 1 && (tt) < Tact) ST(PB, PL) }

#define PROCG(s, tb) { STG(B##s##a.x, L##s##a.x, (tb)+0) STG(B##s##a.y, L##s##a.y, (tb)+1) \
                       STG(B##s##a.z, L##s##a.z, (tb)+2) STG(B##s##a.w, L##s##a.w, (tb)+3) \
                       STG(B##s##b.x, L##s##b.x, (tb)+4) STG(B##s##b.y, L##s##b.y, (tb)+5) \
                       STG(B##s##b.z, L##s##b.z, (tb)+6) STG(B##s##b.w, L##s##b.w, (tb)+7) }

  LOADW(0, 0) LOADW(1, 8) LOADW(2, 16) LOADW(3, 24)

  // t=0 init: alpha[0]=lp_blank(0) at lane0.s0, alpha[1]=lp_label0(0) at lane0.s1
  float s0 = (lane == 0) ? B0a.x : NEGF;
  float s1 = (lane == 0) ? L0a.x : NEGF;
  float s2 = NEGF;

  PROCG(0, 0)            // steps 1..7 (t=0 skipped by guard)
  LOADW(0, 32)
  int t0 = 8;
  for (;;) {
    if (t0 + 8 > Tact) break;
    PROCF(1) LOADW(1, t0 + 32) t0 += 8;
    if (t0 + 8 > Tact) break;
    PROCF(2) LOADW(2, t0 + 32) t0 += 8;
    if (t0 + 8 > Tact) break;
    PROCF(3) LOADW(3, t0 + 32) t0 += 8;
    if (t0 + 8 > Tact) break;
    PROCF(0) LOADW(0, t0 + 32) t0 += 8;
  }
  if (t0 < Tact) { LOADW(0, t0) PROCG(0, t0) }

#undef LOADW
#undef ST
#undef PROCF
#undef STG
#undef PROCG

  __shared__ float A_[132];
  A_[2 * lane] = s0;
  A_[2 * lane + 1] = s1;
  if (lane == 63) A_[128] = s2;
  __syncthreads();
  if (lane == 0) {
    int sl = 2 * ll;
    float a1 = A_[sl];
    float a2 = (sl >= 1) ? A_[sl - 1] : NEGF;
    loss[b] = -ladd2(a1, a2) * LN2;   // log2 -> natural log
  }
}

// ============================================================================
// Kernel 3: sum per-batch losses -> d_out[0]
// ============================================================================
__global__ __launch_bounds__(64) void k_sum(const float* __restrict__ loss,
                                            float* __restrict__ out, int B) {
  int lane = threadIdx.x;
  float s = 0.0f;
  for (int i = lane; i < B; i += 64) s += loss[i];
#pragma unroll
  for (int off = 32; off >= 1; off >>= 1) s += __shfl_xor(s, off, 64);
  if (lane == 0) out[0] = s;
}

extern "C" void kernel_launch(void* const* d_in, const int* in_sizes, int n_in,
                              void* d_out, int out_size, void* d_ws, size_t ws_size,
                              hipStream_t stream) {
  const float* acts       = (const float*)d_in[0];
  const int*   labels     = (const int*)d_in[1];
  const int*   act_lens   = (const int*)d_in[2];
  const int*   label_lens = (const int*)d_in[3];

  const int B = in_sizes[2];
  const int L = in_sizes[1] / B;
  const int T = 1000;   // per reference setup_inputs
  const int V = (int)((long long)in_sizes[0] / ((long long)T * (long long)B));
  const int Tp = (T + 31) & ~31;   // padded channel stride (1024 for T=1000)

  float* lp    = (float*)d_ws;                              // B*(L+1)*Tp floats
  float* lossb = lp + (size_t)B * (size_t)(L + 1) * (size_t)Tp;

  k_prob_gather<<<dim3((T * B + 3) / 4), dim3(256), 0, stream>>>(
      acts, labels, lp, T, Tp, B, V, L);
  k_ctc_fwd<<<dim3(B), dim3(64), 0, stream>>>(lp, labels, act_lens, label_lens,
                                              lossb, T, Tp, B, L);
  k_sum<<<dim3(1), dim3(64), 0, stream>>>(lossb, (float*)d_out, B);
}

// Round 5
// 223.999 us; speedup vs baseline: 1.6374x; 1.1184x over previous
//
#include <hip/hip_runtime.h>
#include <stdint.h>

#define NEGF   (-1.0e30f)
#define LOG2E  1.4426950408889634f
#define LN2    0.6931471805599453f

typedef float v4f __attribute__((ext_vector_type(4)));

// lane i <- lane i-1 (wave_shr:1 = 0x138), lane 0 <- NEGF (old value, bound_ctrl=false)
__device__ __forceinline__ float dpp_shr1(float x) {
  int r = __builtin_amdgcn_update_dpp(__float_as_int(NEGF), __float_as_int(x),
                                      0x138, 0xf, 0xf, false);
  return __int_as_float(r);
}

__device__ __forceinline__ float ladd2(float a, float b) {
  float m = fmaxf(a, b);
  float n = fminf(a, b);
  return m + log2f(1.0f + exp2f(n - m));
}

// ============================================================================
// Kernel 1: per (t,b) row: logsumexp over V, emit LOG2-softmax probs,
// transposed layout lp[b][c][t], c=0 blank, c=1..L labels, stride Tp floats.
// ============================================================================
__global__ __launch_bounds__(256) void k_prob_gather(
    const float* __restrict__ acts, const int* __restrict__ labels,
    float* __restrict__ lp, int T, int Tp, int B, int V, int L) {
  const int lane = threadIdx.x & 63;
  const uint32_t r = blockIdx.x * 4u + (threadIdx.x >> 6);
  if (r >= (uint32_t)(T * B)) return;
  const uint32_t b = r / (uint32_t)T;
  const uint32_t t = r % (uint32_t)T;
  const float* __restrict__ row = acts + ((size_t)t * (size_t)B + b) * (size_t)V;

  float mx, l2s;
  if (V == 2048) {
    const float4* row4 = (const float4*)row;
    float vals[32];
    mx = -3.0e38f;
#pragma unroll
    for (int q = 0; q < 8; ++q) {
      float4 v = row4[lane + (q << 6)];
      vals[q*4+0] = v.x; vals[q*4+1] = v.y; vals[q*4+2] = v.z; vals[q*4+3] = v.w;
      mx = fmaxf(mx, fmaxf(fmaxf(v.x, v.y), fmaxf(v.z, v.w)));
    }
#pragma unroll
    for (int off = 32; off >= 1; off >>= 1) mx = fmaxf(mx, __shfl_xor(mx, off, 64));
    float s = 0.0f;
#pragma unroll
    for (int k = 0; k < 32; ++k) s += exp2f((vals[k] - mx) * LOG2E);
#pragma unroll
    for (int off = 32; off >= 1; off >>= 1) s += __shfl_xor(s, off, 64);
    l2s = log2f(s);
  } else {
    float m = -3.0e38f, s = 0.0f;
    for (int i = lane; i < V; i += 64) {
      float x = row[i];
      float m2 = fmaxf(m, x);
      s = s * exp2f((m - m2) * LOG2E) + exp2f((x - m2) * LOG2E);
      m = m2;
    }
#pragma unroll
    for (int off = 32; off >= 1; off >>= 1) {
      float mo = __shfl_xor(m, off, 64), so = __shfl_xor(s, off, 64);
      float m2 = fmaxf(m, mo);
      s = s * exp2f((m - m2) * LOG2E) + so * exp2f((mo - m2) * LOG2E);
      m = m2;
    }
    mx = m;
    l2s = log2f(s);
  }

  float* __restrict__ out = lp + (size_t)b * (size_t)(L + 1) * (size_t)Tp;
  if (lane < L) {
    int lab = labels[b * (uint32_t)L + lane];
    out[(size_t)(1 + lane) * Tp + t] = (row[lab] - mx) * LOG2E - l2s;
  }
  if (lane == 0) out[t] = (row[0] - mx) * LOG2E - l2s;
}

// ============================================================================
// Kernel 2: CTC forward recurrence, LOG2 domain, one wave per batch element.
// Lane i owns states s0=2i (blank), s1=2i+1 (label i); s2 duplicates state
// 2i+2 (lane 63's s2 = terminal blank 2L). Single DPP per step.
// Prefetch pipeline is INLINE ASM so the compiler cannot sink the loads:
// 4 windows x 8 steps, 16 dwordx4 loads in flight, data-dependent
// s_waitcnt vmcnt(12) gates each window's consumption.
// ============================================================================
__global__ __launch_bounds__(64) void k_ctc_fwd(
    const float* __restrict__ lp, const int* __restrict__ labels,
    const int* __restrict__ act_lens, const int* __restrict__ label_lens,
    float* __restrict__ loss, int T, int Tp, int B, int L) {
  const int b = blockIdx.x;
  const int lane = threadIdx.x;
  const int Tact = __builtin_amdgcn_readfirstlane(min(act_lens[b], T));
  const int ll   = __builtin_amdgcn_readfirstlane(min(label_lens[b], L));

  const float* __restrict__ chb = lp + (size_t)b * (size_t)(L + 1) * (size_t)Tp;
  const int lclamp = (lane < L) ? lane : (L - 1);
  const float* __restrict__ chl = chb + (size_t)(1 + lclamp) * (size_t)Tp;

  int lab_i = (lane < L) ? labels[(size_t)b * L + lane] : 0;
  int lab_p = (lane >= 1 && lane - 1 < L) ? labels[(size_t)b * L + lane - 1] : -1;
  const bool allow2 = (lane >= 1) && (lab_i != 0) && (lab_i != lab_p);

  v4f L0a,L0b,B0a,B0b, L1a,L1b,B1a,B1b, L2a,L2b,B2a,B2b, L3a,L3b,B3a,B3b;

  // drain the compiler's own prologue loads so manual vmcnt bookkeeping is exact
  asm volatile("s_waitcnt vmcnt(0) lgkmcnt(0)" ::: "memory");
  __builtin_amdgcn_sched_barrier(0);

#define LOADW(s, tt) { int tc = (tt); if (tc > Tp - 8) tc = Tp - 8;          \
    const float* pl_ = chl + tc; const float* pb_ = chb + tc;                \
    asm volatile("global_load_dwordx4 %0, %4, off\n\t"                       \
                 "global_load_dwordx4 %1, %4, off offset:16\n\t"             \
                 "global_load_dwordx4 %2, %5, off\n\t"                       \
                 "global_load_dwordx4 %3, %5, off offset:16"                 \
                 : "=&v"(L##s##a), "=&v"(L##s##b),                           \
                   "=&v"(B##s##a), "=&v"(B##s##b)                            \
                 : "v"(pl_), "v"(pb_)); }

  // hardware wait + data dependence: consumers of window s cannot move above
#define WAITW(s, N) asm volatile("s_waitcnt vmcnt(" #N ")"                   \
                 : "+v"(L##s##a), "+v"(L##s##b), "+v"(B##s##a), "+v"(B##s##b));

  // log2-domain step; PB = log2 p_blank(t), PL = log2 p_label(t)
#define ST(PB, PL) { float pa = dpp_shr1(s1);                                \
    float c2 = allow2 ? pa : NEGF;                                           \
    float m0 = fmaxf(s0, pa), n0 = fminf(s0, pa);                            \
    float ns0 = (m0 + (PB)) + log2f(1.0f + exp2f(n0 - m0));                  \
    float m1 = fmaxf(fmaxf(s1, s0), c2);                                     \
    float sS = exp2f(s1 - m1) + exp2f(s0 - m1) + exp2f(c2 - m1);             \
    float ns1 = (m1 + (PL)) + log2f(sS);                                     \
    float m2 = fmaxf(s2, s1), n2 = fminf(s2, s1);                            \
    float ns2 = (m2 + (PB)) + log2f(1.0f + exp2f(n2 - m2));                  \
    s0 = ns0; s1 = ns1; s2 = ns2; }

#define PROCF(s) { ST(B##s##a.x, L##s##a.x) ST(B##s##a.y, L##s##a.y)         \
                   ST(B##s##a.z, L##s##a.z) ST(B##s##a.w, L##s##a.w)         \
                   ST(B##s##b.x, L##s##b.x) ST(B##s##b.y, L##s##b.y)         \
                   ST(B##s##b.z, L##s##b.z) ST(B##s##b.w, L##s##b.w) }

#define STG(PB, PL, tt) { if ((tt) >= 1 && (tt) < Tact) ST(PB, PL) }

#define PROCG(s, tb) { STG(B##s##a.x, L##s##a.x, (tb)+0) STG(B##s##a.y, L##s##a.y, (tb)+1) \
                       STG(B##s##a.z, L##s##a.z, (tb)+2) STG(B##s##a.w, L##s##a.w, (tb)+3) \
                       STG(B##s##b.x, L##s##b.x, (tb)+4) STG(B##s##b.y, L##s##b.y, (tb)+5) \
                       STG(B##s##b.z, L##s##b.z, (tb)+6) STG(B##s##b.w, L##s##b.w, (tb)+7) }

  LOADW(0, 0) LOADW(1, 8) LOADW(2, 16) LOADW(3, 24)
  WAITW(0, 12)

  // t=0 init: alpha[0]=lp_blank(0) at lane0.s0, alpha[1]=lp_label0(0) at lane0.s1
  float s0 = (lane == 0) ? B0a.x : NEGF;
  float s1 = (lane == 0) ? L0a.x : NEGF;
  float s2 = NEGF;

  PROCG(0, 0)            // steps 1..7 (t=0 skipped by guard)
  LOADW(0, 32)
  int t0 = 8;
  for (;;) {
    if (t0 + 8 > Tact) break;
    WAITW(1, 12) PROCF(1) LOADW(1, t0 + 32) t0 += 8;
    if (t0 + 8 > Tact) break;
    WAITW(2, 12) PROCF(2) LOADW(2, t0 + 32) t0 += 8;
    if (t0 + 8 > Tact) break;
    WAITW(3, 12) PROCF(3) LOADW(3, t0 + 32) t0 += 8;
    if (t0 + 8 > Tact) break;
    WAITW(0, 12) PROCF(0) LOADW(0, t0 + 32) t0 += 8;
  }
  if (t0 < Tact) { LOADW(0, t0) WAITW(0, 0) PROCG(0, t0) }

#undef LOADW
#undef WAITW
#undef ST
#undef PROCF
#undef STG
#undef PROCG

  __shared__ float A_[132];
  A_[2 * lane] = s0;
  A_[2 * lane + 1] = s1;
  if (lane == 63) A_[128] = s2;
  __syncthreads();
  if (lane == 0) {
    int sl = 2 * ll;
    float a1 = A_[sl];
    float a2 = (sl >= 1) ? A_[sl - 1] : NEGF;
    loss[b] = -ladd2(a1, a2) * LN2;   // log2 -> natural log
  }
}

// ============================================================================
// Kernel 3: sum per-batch losses -> d_out[0]
// ============================================================================
__global__ __launch_bounds__(64) void k_sum(const float* __restrict__ loss,
                                            float* __restrict__ out, int B) {
  int lane = threadIdx.x;
  float s = 0.0f;
  for (int i = lane; i < B; i += 64) s += loss[i];
#pragma unroll
  for (int off = 32; off >= 1; off >>= 1) s += __shfl_xor(s, off, 64);
  if (lane == 0) out[0] = s;
}

extern "C" void kernel_launch(void* const* d_in, const int* in_sizes, int n_in,
                              void* d_out, int out_size, void* d_ws, size_t ws_size,
                              hipStream_t stream) {
  const float* acts       = (const float*)d_in[0];
  const int*   labels     = (const int*)d_in[1];
  const int*   act_lens   = (const int*)d_in[2];
  const int*   label_lens = (const int*)d_in[3];

  const int B = in_sizes[2];
  const int L = in_sizes[1] / B;
  const int T = 1000;   // per reference setup_inputs
  const int V = (int)((long long)in_sizes[0] / ((long long)T * (long long)B));
  const int Tp = (T + 31) & ~31;   // padded channel stride (1024 for T=1000)

  float* lp    = (float*)d_ws;                              // B*(L+1)*Tp floats
  float* lossb = lp + (size_t)B * (size_t)(L + 1) * (size_t)Tp;

  k_prob_gather<<<dim3((T * B + 3) / 4), dim3(256), 0, stream>>>(
      acts, labels, lp, T, Tp, B, V, L);
  k_ctc_fwd<<<dim3(B), dim3(64), 0, stream>>>(lp, labels, act_lens, label_lens,
                                              lossb, T, Tp, B, L);
  k_sum<<<dim3(1), dim3(64), 0, stream>>>(lossb, (float*)d_out, B);
}